// Round 6
// baseline (1499.965 us; speedup 1.0000x reference)
//
#include <hip/hip_runtime.h>
#include <cstdint>
#include <cstddef>

// ---------------------------------------------------------------------------
// PortOpt_DL_DeepSig round 6:
//  - adaptive t-windows (proven r3/r5); fp32 scan chain
//  - scanC writes stream PACKED (bf16hi<<16 | bf16lo) in place (4B/elem,
//    flat-K im2col preserved); W pre-packed
//  - GEMM v4: M128xN64 block, 4 waves x (32x64), split-K (4 with fallback),
//    conflict-free XOR swizzle, reg-staged issue-early/write-late, v_perm
//    unpack, 3-pass MFMA (ah*bh + ah*bl + al*bh)
// ---------------------------------------------------------------------------

#define BATCH 128
#define LSEQ  256
#define CIN   8
#define L1P   252
#define NS1   251
#define SC1   2954    // 14 + 196 + 2744
#define TOUT  247
#define OCH   64
#define SC2   819     // 9 + 81 + 729
#define NSTK  50
#define KFLAT 14770   // 5*2954
#define KP    14784   // padded to 231*64
#define NKCH  231

typedef __attribute__((ext_vector_type(8))) short short8;
typedef __attribute__((ext_vector_type(16))) float f32x16;

__device__ __forceinline__ unsigned int pack2(float x) {
  unsigned int u = __float_as_uint(x);
  unsigned int hi = u >> 16;                       // truncated bf16 hi
  float rem = x - __uint_as_float(hi << 16);       // exact remainder
  unsigned int v = __float_as_uint(rem);
  unsigned int lo = (v + 0x7FFFu + ((v >> 16) & 1u)) >> 16;  // RNE bf16 lo
  return (hi << 16) | lo;
}

// ---------------- BN stats ----------------
__global__ __launch_bounds__(256) void k_bn(const float* __restrict__ x,
                                            const float* __restrict__ gamma,
                                            const float* __restrict__ beta,
                                            float* __restrict__ scale,
                                            float* __restrict__ shift) {
  int l = blockIdx.x, tid = threadIdx.x;
  float s = 0.f, q = 0.f;
#pragma unroll
  for (int p = 0; p < 4; ++p) {
    int e = tid + p * 256;
    int b = e >> 3, c = e & 7;
    float v = x[((size_t)b * LSEQ + l) * CIN + c];
    s += v; q += v * v;
  }
  for (int d = 32; d; d >>= 1) { s += __shfl_xor(s, d); q += __shfl_xor(q, d); }
  __shared__ float ss[4], qq[4];
  int w = tid >> 6;
  if ((tid & 63) == 0) { ss[w] = s; qq[w] = q; }
  __syncthreads();
  if (tid == 0) {
    float S = ss[0] + ss[1] + ss[2] + ss[3];
    float Q = qq[0] + qq[1] + qq[2] + qq[3];
    float mean = S * (1.f / 1024.f);
    float var  = Q * (1.f / 1024.f) - mean * mean;
    float istd = 1.0f / sqrtf(var + 1e-5f);
    float sc = istd * gamma[l];
    scale[l] = sc;
    shift[l] = beta[l] - mean * sc;
  }
}

// ---------------- Augment 1: path1 (B, 252, 14) ----------------
__global__ __launch_bounds__(256) void k_aug1(const float* __restrict__ x,
                                              const float* __restrict__ scale,
                                              const float* __restrict__ shift,
                                              const float* __restrict__ w1,
                                              const float* __restrict__ b1,
                                              const float* __restrict__ w2,
                                              const float* __restrict__ b2,
                                              float* __restrict__ P1) {
  __shared__ float w1s[400], b1s[10], w2s[50], b2s[5];
  int tid = threadIdx.x;
  for (int i = tid; i < 400; i += 256) w1s[i] = w1[i];
  if (tid < 10) b1s[tid] = b1[tid];
  if (tid < 50) w2s[tid] = w2[tid];
  if (tid < 5)  b2s[tid] = b2[tid];
  __syncthreads();
  int g = blockIdx.x * 256 + tid;
  if (g >= BATCH * L1P) return;
  int b = g / L1P, t = g % L1P;
  float xn[5][8];
#pragma unroll
  for (int k = 0; k < 5; ++k) {
    int l = t + k;
    float sc = scale[l], sh = shift[l];
#pragma unroll
    for (int c = 0; c < 8; ++c)
      xn[k][c] = x[((size_t)b * LSEQ + l) * CIN + c] * sc + sh;
  }
  float r10[10];
#pragma unroll
  for (int co = 0; co < 10; ++co) {
    float s = b1s[co];
#pragma unroll
    for (int c = 0; c < 8; ++c)
#pragma unroll
      for (int k = 0; k < 5; ++k)
        s += xn[k][c] * w1s[co * 40 + c * 5 + k];
    r10[co] = fmaxf(s, 0.f);
  }
  float* o = P1 + ((size_t)b * L1P + t) * 14;
#pragma unroll
  for (int c = 0; c < 8; ++c) o[c] = xn[4][c];
  o[8] = (float)t * (1.0f / 251.0f);
#pragma unroll
  for (int oo = 0; oo < 5; ++oo) {
    float s = b2s[oo];
#pragma unroll
    for (int co = 0; co < 10; ++co) s += r10[co] * w2s[oo * 10 + co];
    o[9 + oo] = s;
  }
}

// ---------------- W -> [o][kflat] packed uint, zero padded ----------------
__global__ __launch_bounds__(256) void k_wtp(const float* __restrict__ w,
                                             unsigned int* __restrict__ Wp) {
  int idx = blockIdx.x * 256 + threadIdx.x;
  if (idx >= OCH * KP) return;
  int o = idx / KP, kf = idx % KP;
  float v = 0.f;
  if (kf < KFLAT) {
    int tap = kf / SC1, c = kf % SC1;
    v = w[((size_t)o * SC1 + c) * 5 + tap];
  }
  Wp[idx] = pack2(v);
}

// ---------------- scan pass A: window chunk-local signatures (fp32) --------
__global__ __launch_bounds__(256) void k_scanA(const float* __restrict__ P1,
                                               float* __restrict__ Sw,
                                               int NRbuf, int w0, int RW) {
  int s = blockIdx.x, b = blockIdx.y, tid = threadIdx.x;
  int r0 = s * 16;
  int cnt = RW - r0; if (cnt > 16) cnt = 16;
  if (cnt <= 0) return;
  const float* p = P1 + (size_t)b * L1P * 14 + (size_t)(w0 + r0) * 14;
  float* Sb = Sw + ((size_t)b * NRbuf + r0) * SC1;
  __shared__ float a1s[14], a2s[196], vs[2][14], b2s[2][196];
  float a3[11];
  int ia[11], i2[11], il2[11], ik[11];
#pragma unroll
  for (int n = 0; n < 11; ++n) {
    int e = tid + n * 256;
    ia[n] = e / 196; i2[n] = e / 14; il2[n] = e % 196; ik[n] = e % 14;
  }
  if (tid < 14) vs[0][tid] = p[14 + tid] - p[tid];
  if (tid < 196) {
    int j = tid / 14, k = tid % 14;
    b2s[0][tid] = 0.5f * (p[14 + j] - p[j]) * (p[14 + k] - p[k]);
  }
  __syncthreads();
  for (int j = 0; j < cnt; ++j) {
    int buf = j & 1;
    float c1n = 0.f, c2n = 0.f;
    if (j == 0) {
      if (tid < 14)  c1n = vs[buf][tid];
      if (tid < 196) c2n = b2s[buf][tid];
#pragma unroll
      for (int n = 0; n < 11; ++n) {
        int e = tid + n * 256;
        if (e < 2744) a3[n] = vs[buf][ia[n]] * b2s[buf][il2[n]] * (1.f / 3.f);
      }
    } else {
#pragma unroll
      for (int n = 0; n < 11; ++n) {
        int e = tid + n * 256;
        if (e < 2744)
          a3[n] += (a1s[ia[n]] + vs[buf][ia[n]] * (1.f / 3.f)) * b2s[buf][il2[n]]
                 + a2s[i2[n]] * vs[buf][ik[n]];
      }
      if (tid < 196) c2n = a2s[tid] + b2s[buf][tid] + a1s[tid / 14] * vs[buf][tid % 14];
      if (tid < 14)  c1n = a1s[tid] + vs[buf][tid];
    }
    __syncthreads();
    if (tid < 14)  a1s[tid] = c1n;
    if (tid < 196) a2s[tid] = c2n;
    {
      float* o = Sb + (size_t)j * SC1;
      if (tid < 14)  o[tid] = c1n;
      if (tid < 196) o[14 + tid] = c2n;
#pragma unroll
      for (int n = 0; n < 11; ++n) {
        int e = tid + n * 256;
        if (e < 2744) o[210 + e] = a3[n];
      }
    }
    if (j + 1 < cnt) {
      int nb = buf ^ 1;
      const float* pj = p + (size_t)(j + 1) * 14;
      if (tid < 14) vs[nb][tid] = pj[14 + tid] - pj[tid];
      if (tid < 196) {
        int jj = tid / 14, kk = tid % 14;
        b2s[nb][tid] = 0.5f * (pj[14 + jj] - pj[jj]) * (pj[14 + kk] - pj[kk]);
      }
    }
    __syncthreads();
  }
}

// ---------------- scan pass B: prefix of chunk totals + carry ---------------
__global__ __launch_bounds__(256) void k_scanB(const float* __restrict__ Sw,
                                               float* __restrict__ Pfx,
                                               float* __restrict__ carry,
                                               int NRbuf, int RW, int NC, int NCC) {
  int b = blockIdx.x, tid = threadIdx.x;
  __shared__ float a1s[14], a2s[196], b1s[14], b2s[196];
  float a3[11], b3[11];
  int ia[11], i2[11], il2[11], ik[11];
#pragma unroll
  for (int n = 0; n < 11; ++n) {
    int e = tid + n * 256;
    ia[n] = e / 196; i2[n] = e / 14; il2[n] = e % 196; ik[n] = e % 14;
  }
  const float* Sb = Sw + (size_t)b * NRbuf * SC1;
  float* cb = carry + (size_t)b * SC1;
  if (tid < 14)  a1s[tid] = cb[tid];
  if (tid < 196) a2s[tid] = cb[14 + tid];
#pragma unroll
  for (int n = 0; n < 11; ++n) { int e = tid + n * 256; if (e < 2744) a3[n] = cb[210 + e]; }
  __syncthreads();
  for (int s = 0; s < NC; ++s) {
    int cnt = RW - s * 16; if (cnt > 16) cnt = 16;
    const float* tr = Sb + (size_t)(s * 16 + cnt - 1) * SC1;
    if (tid < 14)  b1s[tid] = tr[tid];
    if (tid < 196) b2s[tid] = tr[14 + tid];
#pragma unroll
    for (int n = 0; n < 11; ++n) { int e = tid + n * 256; if (e < 2744) b3[n] = tr[210 + e]; }
    __syncthreads();
    float* ps = Pfx + ((size_t)b * 16 + s) * SC1;
    if (tid < 14)  ps[tid] = a1s[tid];
    if (tid < 196) ps[14 + tid] = a2s[tid];
#pragma unroll
    for (int n = 0; n < 11; ++n) { int e = tid + n * 256; if (e < 2744) ps[210 + e] = a3[n]; }
#pragma unroll
    for (int n = 0; n < 11; ++n) {
      int e = tid + n * 256;
      if (e < 2744) a3[n] += b3[n] + a1s[ia[n]] * b2s[il2[n]] + a2s[i2[n]] * b1s[ik[n]];
    }
    float c1n = 0.f, c2n = 0.f;
    if (tid < 196) c2n = a2s[tid] + b2s[tid] + a1s[tid / 14] * b1s[tid % 14];
    if (tid < 14)  c1n = a1s[tid] + b1s[tid];
    __syncthreads();
    if (tid < 14)  a1s[tid] = c1n;
    if (tid < 196) a2s[tid] = c2n;
    if (s == NCC - 1) {
      if (tid < 14)  cb[tid] = c1n;
      if (tid < 196) cb[14 + tid] = c2n;
#pragma unroll
      for (int n = 0; n < 11; ++n) { int e = tid + n * 256; if (e < 2744) cb[210 + e] = a3[n]; }
    }
  }
}

// ---------------- scan pass C: parallel row fixup, writes PACKED ------------
__global__ __launch_bounds__(256) void k_scanC3(float* __restrict__ Sw,
                                                const float* __restrict__ Pfx,
                                                int NRbuf, int RW) {
  int s = blockIdx.x, b = blockIdx.y, tid = threadIdx.x;
  int r0 = s * 16;
  int rows = RW - r0; if (rows > 16) rows = 16;
  if (rows <= 0) return;
  __shared__ float pa[SC1];
  __shared__ float lb[4][216];
  const float* P = Pfx + ((size_t)b * 16 + s) * SC1;
  for (int i = tid; i < SC1; i += 256) pa[i] = P[i];
  __syncthreads();
  int w = tid >> 6, lane = tid & 63;
  float* base = Sw + ((size_t)b * NRbuf + r0) * SC1;
#pragma unroll
  for (int j = 0; j < 4; ++j) {
    int rr = w + j * 4;
    if (rr < rows) {
      float* row = base + (size_t)rr * SC1;
      unsigned int* rowp = (unsigned int*)row;
      if (lane < 53) {
        float4 v = *(const float4*)(row + lane * 4);
        *(float4*)&lb[w][lane * 4] = v;
      }
      asm volatile("s_waitcnt lgkmcnt(0)" ::: "memory");
      for (int c = lane; c < SC1; c += 64) {
        float v = row[c];
        float f;
        if (c < 14) {
          f = pa[c] + v;
        } else if (c < 210) {
          int e = c - 14;
          f = pa[c] + v + pa[e / 14] * lb[w][e % 14];
        } else {
          int e = c - 210;
          int i3 = e / 196, rjk = e - i3 * 196;
          int i2 = e / 14,  kk  = e - i2 * 14;
          f = pa[c] + v + pa[i3] * lb[w][14 + rjk] + pa[14 + i2] * lb[w][kk];
        }
        rowp[c] = pack2(f);
      }
    }
  }
}

// ---------------- MFMA GEMM v4: M128xN64, 4 waves x (32x64), split-K --------
__global__ __launch_bounds__(256, 3) void k_gemm4(const unsigned int* __restrict__ Sp,
                                                  const unsigned int* __restrict__ Wp,
                                                  float* __restrict__ Cpart,
                                                  int NRbuf, int w0, int WTcur,
                                                  int nks, int cpk) {
  const int mt = blockIdx.x / nks, ksid = blockIdx.x % nks;
  const int b = blockIdx.y;
  const int tid = threadIdx.x, lane = tid & 63, w = tid >> 6;
  __shared__ unsigned int As[128 * 64];   // 32 KB, swizzled
  __shared__ unsigned int Bs[64 * 64];    // 16 KB, swizzled
  f32x16 acc0, acc1;
#pragma unroll
  for (int i = 0; i < 16; ++i) { acc0[i] = 0.f; acc1[i] = 0.f; }

  const unsigned int* Sb = Sp + (size_t)b * ((size_t)NRbuf * SC1);
  const int slot = tid & 15;            // 16B slot in 256B row-chunk
  const int rsub = (tid >> 4) & 3;      // row within 4-row instr group
  uint4 ra[8], rb[4];
  const int c0 = ksid * cpk;
  int c1 = c0 + cpk; if (c1 > NKCH) c1 = NKCH;

  auto GLOAD = [&](int ch) {
    const int k0 = ch * 64;
#pragma unroll
    for (int p = 0; p < 8; ++p) {
      int rl = w * 32 + p * 4 + rsub;
      int t = mt * 128 + rl; if (t > WTcur - 1) t = WTcur - 1;
      ra[p] = *(const uint4*)(Sb + (size_t)t * SC1 + k0 + slot * 4);
    }
#pragma unroll
    for (int p = 0; p < 4; ++p) {
      int o = w * 16 + p * 4 + rsub;
      rb[p] = *(const uint4*)(Wp + (size_t)o * KP + k0 + slot * 4);
    }
  };
  auto SSTORE = [&]() {
#pragma unroll
    for (int p = 0; p < 8; ++p) {
      int rl = w * 32 + p * 4 + rsub;
      *(uint4*)&As[rl * 64 + ((slot ^ (rl & 15)) << 2)] = ra[p];
    }
#pragma unroll
    for (int p = 0; p < 4; ++p) {
      int o = w * 16 + p * 4 + rsub;
      *(uint4*)&Bs[o * 64 + ((slot ^ (o & 15)) << 2)] = rb[p];
    }
  };

  GLOAD(c0);
  SSTORE();
  __syncthreads();

  const int rA = w * 32 + (lane & 31);
  const int cB0 = lane & 31, cB1 = cB0 + 32;
  const int swA = rA & 15, swB = cB0 & 15;
  const int hsh = (lane >> 5) << 1;

  union U { unsigned int u[4]; short8 s; };

  for (int ch = c0; ch < c1; ++ch) {
    if (ch + 1 < c1) GLOAD(ch + 1);    // issue early (T14)
#pragma unroll
    for (int ks = 0; ks < 4; ++ks) {
      const int s0 = ks * 4 + hsh;
      const uint4 aA = *(const uint4*)&As[rA * 64 + ((s0 ^ swA) << 2)];
      const uint4 aB = *(const uint4*)&As[rA * 64 + (((s0 + 1) ^ swA) << 2)];
      const uint4 p0 = *(const uint4*)&Bs[cB0 * 64 + ((s0 ^ swB) << 2)];
      const uint4 p1 = *(const uint4*)&Bs[cB0 * 64 + (((s0 + 1) ^ swB) << 2)];
      const uint4 q0 = *(const uint4*)&Bs[cB1 * 64 + ((s0 ^ swB) << 2)];
      const uint4 q1 = *(const uint4*)&Bs[cB1 * 64 + (((s0 + 1) ^ swB) << 2)];
      U ah, al, b0h, b0l, b1h, b1l;
      ah.u[0] = __builtin_amdgcn_perm(aA.y, aA.x, 0x07060302u);
      ah.u[1] = __builtin_amdgcn_perm(aA.w, aA.z, 0x07060302u);
      ah.u[2] = __builtin_amdgcn_perm(aB.y, aB.x, 0x07060302u);
      ah.u[3] = __builtin_amdgcn_perm(aB.w, aB.z, 0x07060302u);
      al.u[0] = __builtin_amdgcn_perm(aA.y, aA.x, 0x05040100u);
      al.u[1] = __builtin_amdgcn_perm(aA.w, aA.z, 0x05040100u);
      al.u[2] = __builtin_amdgcn_perm(aB.y, aB.x, 0x05040100u);
      al.u[3] = __builtin_amdgcn_perm(aB.w, aB.z, 0x05040100u);
      b0h.u[0] = __builtin_amdgcn_perm(p0.y, p0.x, 0x07060302u);
      b0h.u[1] = __builtin_amdgcn_perm(p0.w, p0.z, 0x07060302u);
      b0h.u[2] = __builtin_amdgcn_perm(p1.y, p1.x, 0x07060302u);
      b0h.u[3] = __builtin_amdgcn_perm(p1.w, p1.z, 0x07060302u);
      b0l.u[0] = __builtin_amdgcn_perm(p0.y, p0.x, 0x05040100u);
      b0l.u[1] = __builtin_amdgcn_perm(p0.w, p0.z, 0x05040100u);
      b0l.u[2] = __builtin_amdgcn_perm(p1.y, p1.x, 0x05040100u);
      b0l.u[3] = __builtin_amdgcn_perm(p1.w, p1.z, 0x05040100u);
      b1h.u[0] = __builtin_amdgcn_perm(q0.y, q0.x, 0x07060302u);
      b1h.u[1] = __builtin_amdgcn_perm(q0.w, q0.z, 0x07060302u);
      b1h.u[2] = __builtin_amdgcn_perm(q1.y, q1.x, 0x07060302u);
      b1h.u[3] = __builtin_amdgcn_perm(q1.w, q1.z, 0x07060302u);
      b1l.u[0] = __builtin_amdgcn_perm(q0.y, q0.x, 0x05040100u);
      b1l.u[1] = __builtin_amdgcn_perm(q0.w, q0.z, 0x05040100u);
      b1l.u[2] = __builtin_amdgcn_perm(q1.y, q1.x, 0x05040100u);
      b1l.u[3] = __builtin_amdgcn_perm(q1.w, q1.z, 0x05040100u);
      acc0 = __builtin_amdgcn_mfma_f32_32x32x16_bf16(ah.s, b0h.s, acc0, 0, 0, 0);
      acc0 = __builtin_amdgcn_mfma_f32_32x32x16_bf16(ah.s, b0l.s, acc0, 0, 0, 0);
      acc0 = __builtin_amdgcn_mfma_f32_32x32x16_bf16(al.s, b0h.s, acc0, 0, 0, 0);
      acc1 = __builtin_amdgcn_mfma_f32_32x32x16_bf16(ah.s, b1h.s, acc1, 0, 0, 0);
      acc1 = __builtin_amdgcn_mfma_f32_32x32x16_bf16(ah.s, b1l.s, acc1, 0, 0, 0);
      acc1 = __builtin_amdgcn_mfma_f32_32x32x16_bf16(al.s, b1h.s, acc1, 0, 0, 0);
    }
    __syncthreads();
    if (ch + 1 < c1) { SSTORE(); __syncthreads(); }
  }

  const size_t part = ((size_t)ksid * BATCH + b) * TOUT * OCH;
#pragma unroll
  for (int q = 0; q < 16; ++q) {
    int crow = (q & 3) + 8 * (q >> 2) + 4 * (lane >> 5);
    int tl = mt * 128 + w * 32 + crow;
    if (tl < WTcur) {
      size_t o = part + (size_t)(w0 + tl) * OCH;
      Cpart[o + cB0] = acc0[q];
      Cpart[o + cB1] = acc1[q];
    }
  }
}

// ---------------- P2: bias + sum split-K partials, relu @ w2, + time --------
__global__ __launch_bounds__(256) void k_p2(const float* __restrict__ Cpart,
                                            const float* __restrict__ bias,
                                            const float* __restrict__ w2,
                                            const float* __restrict__ b2,
                                            float* __restrict__ P2, int nks) {
  int warp = blockIdx.x * 4 + (threadIdx.x >> 6);
  int lane = threadIdx.x & 63;
  int b = warp / TOUT, t = warp % TOUT;
  size_t idx = ((size_t)b * TOUT + t) * OCH + lane;
  const size_t part = (size_t)BATCH * TOUT * OCH;
  float v = bias[lane];
  for (int ks = 0; ks < nks; ++ks) v += Cpart[(size_t)ks * part + idx];
  v = fmaxf(v, 0.f);
  float* o = P2 + ((size_t)b * TOUT + t) * 9;
#pragma unroll
  for (int oo = 0; oo < 8; ++oo) {
    float s = v * w2[oo * 64 + lane];
    for (int d = 32; d; d >>= 1) s += __shfl_xor(s, d);
    if (lane == oo) o[1 + oo] = s + b2[oo];
  }
  if (lane == 8) o[0] = (float)t * (1.0f / 246.0f);
}

// ---------------- final signature pass A: chunk totals ----------------------
__global__ __launch_bounds__(256) void k_sig2A(const float* __restrict__ P2,
                                               float* __restrict__ T2) {
  int ch = blockIdx.x, b = blockIdx.y, tid = threadIdx.x;
  int r0 = ch * 16;
  int steps = 246 - r0; if (steps > 16) steps = 16;
  const float* p = P2 + (size_t)b * TOUT * 9;
  __shared__ float a1s[9], a2s[81], vs[2][9], b2s[2][81];
  float a3[3];
  int ia[3], i2[3], il2[3], ik[3];
#pragma unroll
  for (int n = 0; n < 3; ++n) {
    int e = tid + n * 256;
    ia[n] = e / 81; i2[n] = e / 9; il2[n] = e % 81; ik[n] = e % 9;
  }
  {
    int r = r0;
    if (tid < 9) vs[0][tid] = p[(r + 1) * 9 + tid] - p[r * 9 + tid];
    if (tid < 81) {
      int j = tid / 9, k = tid % 9;
      b2s[0][tid] = 0.5f * (p[(r + 1) * 9 + j] - p[r * 9 + j])
                         * (p[(r + 1) * 9 + k] - p[r * 9 + k]);
    }
  }
  __syncthreads();
  for (int s = 0; s < steps; ++s) {
    int buf = s & 1, r = r0 + s;
    float c1n = 0.f, c2n = 0.f;
    if (s == 0) {
      if (tid < 9)  c1n = vs[buf][tid];
      if (tid < 81) c2n = b2s[buf][tid];
#pragma unroll
      for (int n = 0; n < 3; ++n) {
        int e = tid + n * 256;
        if (e < 729) a3[n] = vs[buf][ia[n]] * b2s[buf][il2[n]] * (1.f / 3.f);
      }
    } else {
#pragma unroll
      for (int n = 0; n < 3; ++n) {
        int e = tid + n * 256;
        if (e < 729)
          a3[n] += (a1s[ia[n]] + vs[buf][ia[n]] * (1.f / 3.f)) * b2s[buf][il2[n]]
                 + a2s[i2[n]] * vs[buf][ik[n]];
      }
      if (tid < 81) c2n = a2s[tid] + b2s[buf][tid] + a1s[tid / 9] * vs[buf][tid % 9];
      if (tid < 9)  c1n = a1s[tid] + vs[buf][tid];
    }
    __syncthreads();
    if (tid < 9)  a1s[tid] = c1n;
    if (tid < 81) a2s[tid] = c2n;
    if (s + 1 < steps) {
      int r2 = r + 1, nb = buf ^ 1;
      if (tid < 9) vs[nb][tid] = p[(r2 + 1) * 9 + tid] - p[r2 * 9 + tid];
      if (tid < 81) {
        int j = tid / 9, k = tid % 9;
        b2s[nb][tid] = 0.5f * (p[(r2 + 1) * 9 + j] - p[r2 * 9 + j])
                            * (p[(r2 + 1) * 9 + k] - p[r2 * 9 + k]);
      }
    }
    __syncthreads();
  }
  {
    float* tb = T2 + ((size_t)b * 16 + ch) * SC2;
    if (tid < 9)  tb[tid] = a1s[tid];
    if (tid < 81) tb[9 + tid] = a2s[tid];
#pragma unroll
    for (int n = 0; n < 3; ++n) {
      int e = tid + n * 256;
      if (e < 729) tb[90 + e] = a3[n];
    }
  }
}

// ---------------- final signature pass B: fold 16 totals --------------------
__global__ __launch_bounds__(256) void k_sig2B(const float* __restrict__ T2,
                                               float* __restrict__ sg) {
  int b = blockIdx.x, tid = threadIdx.x;
  __shared__ float a1s[9], a2s[81], b1s[9], b2s[81];
  float a3[3], b3[3];
  int ia[3], i2[3], il2[3], ik[3];
#pragma unroll
  for (int n = 0; n < 3; ++n) {
    int e = tid + n * 256;
    ia[n] = e / 81; i2[n] = e / 9; il2[n] = e % 81; ik[n] = e % 9;
  }
  const float* base = T2 + (size_t)b * 16 * SC2;
  if (tid < 9)  a1s[tid] = base[tid];
  if (tid < 81) a2s[tid] = base[9 + tid];
#pragma unroll
  for (int n = 0; n < 3; ++n) { int e = tid + n * 256; if (e < 729) a3[n] = base[90 + e]; }
  __syncthreads();
  for (int ch = 1; ch < 16; ++ch) {
    const float* sl = base + (size_t)ch * SC2;
    if (tid < 9)  b1s[tid] = sl[tid];
    if (tid < 81) b2s[tid] = sl[9 + tid];
#pragma unroll
    for (int n = 0; n < 3; ++n) { int e = tid + n * 256; if (e < 729) b3[n] = sl[90 + e]; }
    __syncthreads();
#pragma unroll
    for (int n = 0; n < 3; ++n) {
      int e = tid + n * 256;
      if (e < 729) a3[n] += b3[n] + a1s[ia[n]] * b2s[il2[n]] + a2s[i2[n]] * b1s[ik[n]];
    }
    float c1n = 0.f, c2n = 0.f;
    if (tid < 81) c2n = a2s[tid] + b2s[tid] + a1s[tid / 9] * b1s[tid % 9];
    if (tid < 9)  c1n = a1s[tid] + b1s[tid];
    __syncthreads();
    if (tid < 9)  a1s[tid] = c1n;
    if (tid < 81) a2s[tid] = c2n;
    __syncthreads();
  }
  float* o = sg + (size_t)b * SC2;
  if (tid < 9)  o[tid] = a1s[tid];
  if (tid < 81) o[9 + tid] = a2s[tid];
#pragma unroll
  for (int n = 0; n < 3; ++n) { int e = tid + n * 256; if (e < 729) o[90 + e] = a3[n]; }
}

// ---------------- linear + softmax -----------------------------------------
__global__ __launch_bounds__(64) void k_final(const float* __restrict__ sg,
                                              const float* __restrict__ lw,
                                              const float* __restrict__ lb,
                                              float* __restrict__ out) {
  int b = blockIdx.x, lane = threadIdx.x;
  float logit = -3.402823466e38f;
  if (lane < NSTK) {
    float s = lb[lane];
    const float* w = lw + (size_t)lane * SC2;
    const float* g = sg + (size_t)b * SC2;
    for (int c = 0; c < SC2; ++c) s += g[c] * w[c];
    logit = s;
  }
  float m = logit;
  for (int d = 32; d; d >>= 1) m = fmaxf(m, __shfl_xor(m, d));
  float e = (lane < NSTK) ? expf(logit - m) : 0.f;
  float sum = e;
  for (int d = 32; d; d >>= 1) sum += __shfl_xor(sum, d);
  if (lane < NSTK) out[(size_t)b * NSTK + lane] = e / sum;
}

// ---------------------------------------------------------------------------
extern "C" void kernel_launch(void* const* d_in, const int* in_sizes, int n_in,
                              void* d_out, int out_size, void* d_ws, size_t ws_size,
                              hipStream_t stream) {
  const float* x      = (const float*)d_in[0];
  const float* gamma  = (const float*)d_in[1];
  const float* beta   = (const float*)d_in[2];
  const float* a1w1   = (const float*)d_in[3];
  const float* a1b1   = (const float*)d_in[4];
  const float* a1w2   = (const float*)d_in[5];
  const float* a1b2   = (const float*)d_in[6];
  const float* a2w1   = (const float*)d_in[7];
  const float* a2b1   = (const float*)d_in[8];
  const float* a2w2   = (const float*)d_in[9];
  const float* a2b2   = (const float*)d_in[10];
  const float* lin_w  = (const float*)d_in[11];
  const float* lin_b  = (const float*)d_in[12];
  float* out = (float*)d_out;

  float* ws = (float*)d_ws;
  float*        scale = ws;                       //       256
  float*        shift = ws + 256;                 //       256
  float*        P1    = ws + 512;                 //   451,584
  unsigned int* Wp    = (unsigned int*)(ws + 452096);   // 946,176 uints
  float*        carry = ws + 1398272;             //   378,112
  float*        Pfx   = ws + 1776384;             // 6,049,792 (16 slots)
  float*        P2    = ws + 7826176;             //   284,544
  float*        sig2  = ws + 8110720;             //   104,832
  float*        Cpart = ws + 8215552;             // nks x 2,023,424
  float*        T2    = Pfx;                      // Pfx dead after last scanC

  const size_t PARTSZ = (size_t)BATCH * TOUT * OCH;   // 2,023,424
  size_t ws_floats = ws_size / 4;
  long slot = (long)BATCH * SC1;                       // 378,112 per row-slot

  // choose split-K factor so the adaptive window buffer keeps >= 24 rows
  int nks = 4;
  long off_Swin = 0, avail = 0;
  for (;;) {
    off_Swin = 8215552 + (long)nks * (long)PARTSZ;
    avail = (long)ws_floats - off_Swin - 1024;
    if (nks == 1 || (avail > 0 && avail / slot >= 24)) break;
    nks >>= 1;
  }
  int NRbuf = (int)(avail > 0 ? avail / slot : 0);
  if (NRbuf > 251) NRbuf = 251;
  if (NRbuf < 24)  NRbuf = 24;     // proven-safe floor (round 3/5)
  int WT = (NRbuf >= 251) ? 247 : ((NRbuf - 4) / 16) * 16;
  int nwin = (TOUT + WT - 1) / WT;
  int cpk = (NKCH + nks - 1) / nks;
  float* Swin = ws + off_Swin;

  hipMemsetAsync(carry, 0, (size_t)slot * 4, stream);  // chen identity = zeros

  k_bn  <<<LSEQ, 256, 0, stream>>>(x, gamma, beta, scale, shift);
  k_aug1<<<(BATCH * L1P) / 256, 256, 0, stream>>>(x, scale, shift, a1w1, a1b1, a1w2, a1b2, P1);
  k_wtp <<<(OCH * KP) / 256, 256, 0, stream>>>(a2w1, Wp);

  for (int w = 0; w < nwin; ++w) {
    int w0 = w * WT;
    int WTcur = TOUT - w0; if (WTcur > WT) WTcur = WT;
    int RW = WTcur + 4;
    int NC = (RW + 15) / 16;
    int NCC = (w + 1 < nwin) ? (WT / 16) : -2;
    k_scanA<<<dim3(NC, BATCH), 256, 0, stream>>>(P1, Swin, NRbuf, w0, RW);
    k_scanB<<<BATCH, 256, 0, stream>>>(Swin, Pfx, carry, NRbuf, RW, NC, NCC);
    k_scanC3<<<dim3(NC, BATCH), 256, 0, stream>>>(Swin, Pfx, NRbuf, RW);
    int mtiles = (WTcur + 127) / 128;
    k_gemm4<<<dim3(mtiles * nks, BATCH), 256, 0, stream>>>(
        (const unsigned int*)Swin, Wp, Cpart, NRbuf, w0, WTcur, nks, cpk);
  }

  k_p2   <<<(BATCH * TOUT) / 4, 256, 0, stream>>>(Cpart, a2b1, a2w2, a2b2, P2, nks);
  k_sig2A<<<dim3(16, BATCH), 256, 0, stream>>>(P2, T2);
  k_sig2B<<<BATCH, 256, 0, stream>>>(T2, sig2);
  k_final<<<BATCH, 64, 0, stream>>>(sig2, lin_w, lin_b, out);
}

// Round 9
// 1054.538 us; speedup vs baseline: 1.4224x; 1.4224x over previous
//
#include <hip/hip_runtime.h>
#include <cstdint>
#include <cstddef>

// ---------------------------------------------------------------------------
// PortOpt_DL_DeepSig round 9 (= round 8 resubmitted; round-8 bench never ran:
// GPU acquisition timeout). Single change vs round 7: B-staging offset fix
// (GLOADB used c0*2 with a ushort* base; correct is c0 — one channel = one
// ushort). Everything else identical to the round-7 structure:
//  - D-decomposition GEMM: D[r][tap*64+o] = sum_c S[r][c] * W[o][c][tap]
//    (reads stream once; no im2col 5x HBM amplification); tap-shift in k_p2w
//  - ws-adaptive windows capped at 116 rows (L3-resident stream window)
//  - spill-proof staging (named regs), pre-split hi|lo LDS rows, XOR swizzle
//  - scans: fp32 scanA/B, parallel scanC writes packed (r6-verified)
// ---------------------------------------------------------------------------

#define BATCH 128
#define LSEQ  256
#define CIN   8
#define L1P   252
#define NS1   251
#define SC1   2954    // 14 + 196 + 2744
#define TOUT  247
#define OCH   64
#define SC2   819     // 9 + 81 + 729
#define NSTK  50
#define NB    320     // 5 taps * 64 och
#define KB2   2976    // padded c-length for W rows (93*32)
#define NCH2  93      // K chunks of 32 channels

typedef __attribute__((ext_vector_type(8))) short short8;
typedef __attribute__((ext_vector_type(16))) float f32x16;
typedef unsigned short ushort_t;

__device__ __forceinline__ unsigned int pack2(float x) {
  unsigned int u = __float_as_uint(x);
  unsigned int hi = u >> 16;                       // truncated bf16 hi
  float rem = x - __uint_as_float(hi << 16);       // exact remainder
  unsigned int v = __float_as_uint(rem);
  unsigned int lo = (v + 0x7FFFu + ((v >> 16) & 1u)) >> 16;  // RNE bf16 lo
  return (hi << 16) | lo;
}

// ---------------- BN stats ----------------
__global__ __launch_bounds__(256) void k_bn(const float* __restrict__ x,
                                            const float* __restrict__ gamma,
                                            const float* __restrict__ beta,
                                            float* __restrict__ scale,
                                            float* __restrict__ shift) {
  int l = blockIdx.x, tid = threadIdx.x;
  float s = 0.f, q = 0.f;
#pragma unroll
  for (int p = 0; p < 4; ++p) {
    int e = tid + p * 256;
    int b = e >> 3, c = e & 7;
    float v = x[((size_t)b * LSEQ + l) * CIN + c];
    s += v; q += v * v;
  }
  for (int d = 32; d; d >>= 1) { s += __shfl_xor(s, d); q += __shfl_xor(q, d); }
  __shared__ float ss[4], qq[4];
  int w = tid >> 6;
  if ((tid & 63) == 0) { ss[w] = s; qq[w] = q; }
  __syncthreads();
  if (tid == 0) {
    float S = ss[0] + ss[1] + ss[2] + ss[3];
    float Q = qq[0] + qq[1] + qq[2] + qq[3];
    float mean = S * (1.f / 1024.f);
    float var  = Q * (1.f / 1024.f) - mean * mean;
    float istd = 1.0f / sqrtf(var + 1e-5f);
    float sc = istd * gamma[l];
    scale[l] = sc;
    shift[l] = beta[l] - mean * sc;
  }
}

// ---------------- Augment 1: path1 (B, 252, 14) ----------------
__global__ __launch_bounds__(256) void k_aug1(const float* __restrict__ x,
                                              const float* __restrict__ scale,
                                              const float* __restrict__ shift,
                                              const float* __restrict__ w1,
                                              const float* __restrict__ b1,
                                              const float* __restrict__ w2,
                                              const float* __restrict__ b2,
                                              float* __restrict__ P1) {
  __shared__ float w1s[400], b1s[10], w2s[50], b2s[5];
  int tid = threadIdx.x;
  for (int i = tid; i < 400; i += 256) w1s[i] = w1[i];
  if (tid < 10) b1s[tid] = b1[tid];
  if (tid < 50) w2s[tid] = w2[tid];
  if (tid < 5)  b2s[tid] = b2[tid];
  __syncthreads();
  int g = blockIdx.x * 256 + tid;
  if (g >= BATCH * L1P) return;
  int b = g / L1P, t = g % L1P;
  float xn[5][8];
#pragma unroll
  for (int k = 0; k < 5; ++k) {
    int l = t + k;
    float sc = scale[l], sh = shift[l];
#pragma unroll
    for (int c = 0; c < 8; ++c)
      xn[k][c] = x[((size_t)b * LSEQ + l) * CIN + c] * sc + sh;
  }
  float r10[10];
#pragma unroll
  for (int co = 0; co < 10; ++co) {
    float s = b1s[co];
#pragma unroll
    for (int c = 0; c < 8; ++c)
#pragma unroll
      for (int k = 0; k < 5; ++k)
        s += xn[k][c] * w1s[co * 40 + c * 5 + k];
    r10[co] = fmaxf(s, 0.f);
  }
  float* o = P1 + ((size_t)b * L1P + t) * 14;
#pragma unroll
  for (int c = 0; c < 8; ++c) o[c] = xn[4][c];
  o[8] = (float)t * (1.0f / 251.0f);
#pragma unroll
  for (int oo = 0; oo < 5; ++oo) {
    float s = b2s[oo];
#pragma unroll
    for (int co = 0; co < 10; ++co) s += r10[co] * w2s[oo * 10 + co];
    o[9 + oo] = s;
  }
}

// ---------------- W -> split bf16 hi/lo rows [n=tap*64+o][KB2] --------------
__global__ __launch_bounds__(256) void k_wt3(const float* __restrict__ w,
                                             ushort_t* __restrict__ Wh,
                                             ushort_t* __restrict__ Wl) {
  int idx = blockIdx.x * 256 + threadIdx.x;
  if (idx >= NB * KB2) return;
  int n = idx / KB2, c = idx % KB2;
  int tap = n >> 6, o = n & 63;
  float v = (c < SC1) ? w[((size_t)o * SC1 + c) * 5 + tap] : 0.f;
  unsigned int u = __float_as_uint(v);
  unsigned int hi = u >> 16;                       // trunc (matches pack2)
  float rem = v - __uint_as_float(hi << 16);
  unsigned int r = __float_as_uint(rem);
  unsigned int lo = (r + 0x7FFFu + ((r >> 16) & 1u)) >> 16;
  Wh[idx] = (ushort_t)hi;
  Wl[idx] = (ushort_t)lo;
}

// ---------------- scan pass A: window chunk-local signatures (fp32) ---------
__global__ __launch_bounds__(256) void k_scanA(const float* __restrict__ P1,
                                               float* __restrict__ Sw,
                                               int R, int w0, int RW) {
  int s = blockIdx.x, b = blockIdx.y, tid = threadIdx.x;
  int r0 = s * 16;
  int cnt = RW - r0; if (cnt > 16) cnt = 16;
  if (cnt <= 0) return;
  const float* p = P1 + (size_t)b * L1P * 14 + (size_t)(w0 + r0) * 14;
  float* Sb = Sw + ((size_t)b * R + r0) * SC1;
  __shared__ float a1s[14], a2s[196], vs[2][14], b2s[2][196];
  float a3[11];
  int ia[11], i2[11], il2[11], ik[11];
#pragma unroll
  for (int n = 0; n < 11; ++n) {
    int e = tid + n * 256;
    ia[n] = e / 196; i2[n] = e / 14; il2[n] = e % 196; ik[n] = e % 14;
  }
  if (tid < 14) vs[0][tid] = p[14 + tid] - p[tid];
  if (tid < 196) {
    int j = tid / 14, k = tid % 14;
    b2s[0][tid] = 0.5f * (p[14 + j] - p[j]) * (p[14 + k] - p[k]);
  }
  __syncthreads();
  for (int j = 0; j < cnt; ++j) {
    int buf = j & 1;
    float c1n = 0.f, c2n = 0.f;
    if (j == 0) {
      if (tid < 14)  c1n = vs[buf][tid];
      if (tid < 196) c2n = b2s[buf][tid];
#pragma unroll
      for (int n = 0; n < 11; ++n) {
        int e = tid + n * 256;
        if (e < 2744) a3[n] = vs[buf][ia[n]] * b2s[buf][il2[n]] * (1.f / 3.f);
      }
    } else {
#pragma unroll
      for (int n = 0; n < 11; ++n) {
        int e = tid + n * 256;
        if (e < 2744)
          a3[n] += (a1s[ia[n]] + vs[buf][ia[n]] * (1.f / 3.f)) * b2s[buf][il2[n]]
                 + a2s[i2[n]] * vs[buf][ik[n]];
      }
      if (tid < 196) c2n = a2s[tid] + b2s[buf][tid] + a1s[tid / 14] * vs[buf][tid % 14];
      if (tid < 14)  c1n = a1s[tid] + vs[buf][tid];
    }
    __syncthreads();
    if (tid < 14)  a1s[tid] = c1n;
    if (tid < 196) a2s[tid] = c2n;
    {
      float* o = Sb + (size_t)j * SC1;
      if (tid < 14)  o[tid] = c1n;
      if (tid < 196) o[14 + tid] = c2n;
#pragma unroll
      for (int n = 0; n < 11; ++n) {
        int e = tid + n * 256;
        if (e < 2744) o[210 + e] = a3[n];
      }
    }
    if (j + 1 < cnt) {
      int nb = buf ^ 1;
      const float* pj = p + (size_t)(j + 1) * 14;
      if (tid < 14) vs[nb][tid] = pj[14 + tid] - pj[tid];
      if (tid < 196) {
        int jj = tid / 14, kk = tid % 14;
        b2s[nb][tid] = 0.5f * (pj[14 + jj] - pj[jj]) * (pj[14 + kk] - pj[kk]);
      }
    }
    __syncthreads();
  }
}

// ---------------- scan pass B: prefix of chunk totals + carry ---------------
__global__ __launch_bounds__(256) void k_scanB(const float* __restrict__ Sw,
                                               float* __restrict__ Pfx,
                                               float* __restrict__ carry,
                                               int R, int RW, int NC, int NCC) {
  int b = blockIdx.x, tid = threadIdx.x;
  __shared__ float a1s[14], a2s[196], b1s[14], b2s[196];
  float a3[11], b3[11];
  int ia[11], i2[11], il2[11], ik[11];
#pragma unroll
  for (int n = 0; n < 11; ++n) {
    int e = tid + n * 256;
    ia[n] = e / 196; i2[n] = e / 14; il2[n] = e % 196; ik[n] = e % 14;
  }
  const float* Sb = Sw + (size_t)b * R * SC1;
  float* cb = carry + (size_t)b * SC1;
  if (tid < 14)  a1s[tid] = cb[tid];
  if (tid < 196) a2s[tid] = cb[14 + tid];
#pragma unroll
  for (int n = 0; n < 11; ++n) { int e = tid + n * 256; if (e < 2744) a3[n] = cb[210 + e]; }
  __syncthreads();
  for (int s = 0; s < NC; ++s) {
    int cnt = RW - s * 16; if (cnt > 16) cnt = 16;
    const float* tr = Sb + (size_t)(s * 16 + cnt - 1) * SC1;
    if (tid < 14)  b1s[tid] = tr[tid];
    if (tid < 196) b2s[tid] = tr[14 + tid];
#pragma unroll
    for (int n = 0; n < 11; ++n) { int e = tid + n * 256; if (e < 2744) b3[n] = tr[210 + e]; }
    __syncthreads();
    float* ps = Pfx + ((size_t)b * 16 + s) * SC1;
    if (tid < 14)  ps[tid] = a1s[tid];
    if (tid < 196) ps[14 + tid] = a2s[tid];
#pragma unroll
    for (int n = 0; n < 11; ++n) { int e = tid + n * 256; if (e < 2744) ps[210 + e] = a3[n]; }
#pragma unroll
    for (int n = 0; n < 11; ++n) {
      int e = tid + n * 256;
      if (e < 2744) a3[n] += b3[n] + a1s[ia[n]] * b2s[il2[n]] + a2s[i2[n]] * b1s[ik[n]];
    }
    float c1n = 0.f, c2n = 0.f;
    if (tid < 196) c2n = a2s[tid] + b2s[tid] + a1s[tid / 14] * b1s[tid % 14];
    if (tid < 14)  c1n = a1s[tid] + b1s[tid];
    __syncthreads();
    if (tid < 14)  a1s[tid] = c1n;
    if (tid < 196) a2s[tid] = c2n;
    if (s == NCC - 1) {   // carry = signature through first WT rows
      if (tid < 14)  cb[tid] = c1n;
      if (tid < 196) cb[14 + tid] = c2n;
#pragma unroll
      for (int n = 0; n < 11; ++n) { int e = tid + n * 256; if (e < 2744) cb[210 + e] = a3[n]; }
    }
  }
}

// ---------------- scan pass C: parallel row fixup, writes PACKED ------------
__global__ __launch_bounds__(256) void k_scanC3(float* __restrict__ Sw,
                                                const float* __restrict__ Pfx,
                                                int R, int RW) {
  int s = blockIdx.x, b = blockIdx.y, tid = threadIdx.x;
  int r0 = s * 16;
  int rows = RW - r0; if (rows > 16) rows = 16;
  if (rows <= 0) return;
  __shared__ float pa[SC1];
  __shared__ float lb[4][216];
  const float* P = Pfx + ((size_t)b * 16 + s) * SC1;
  for (int i = tid; i < SC1; i += 256) pa[i] = P[i];
  __syncthreads();
  int w = tid >> 6, lane = tid & 63;
  float* base = Sw + ((size_t)b * R + r0) * SC1;
#pragma unroll
  for (int j = 0; j < 4; ++j) {
    int rr = w + j * 4;
    if (rr < rows) {
      float* row = base + (size_t)rr * SC1;
      unsigned int* rowp = (unsigned int*)row;
      if (lane < 53) {
        float4 v = *(const float4*)(row + lane * 4);
        *(float4*)&lb[w][lane * 4] = v;
      }
      asm volatile("s_waitcnt lgkmcnt(0)" ::: "memory");
      for (int c = lane; c < SC1; c += 64) {
        float v = row[c];
        float f;
        if (c < 14) {
          f = pa[c] + v;
        } else if (c < 210) {
          int e = c - 14;
          f = pa[c] + v + pa[e / 14] * lb[w][e % 14];
        } else {
          int e = c - 210;
          int i3 = e / 196, rjk = e - i3 * 196;
          int i2 = e / 14,  kk  = e - i2 * 14;
          f = pa[c] + v + pa[i3] * lb[w][14 + rjk] + pa[14 + i2] * lb[w][kk];
        }
        rowp[c] = pack2(f);
      }
    }
  }
}

// ---------------- GEMM v5: D[rl][n] = sum_c S[rl][c]*Wb[n][c] ---------------
// tile M64 x N320, K-chunk 32; LDS rows = [hi 64B | lo 64B], unit^(row&3)
__global__ __launch_bounds__(256) void k_gemm5(const unsigned int* __restrict__ Sp,
                                               const ushort_t* __restrict__ Wh,
                                               const ushort_t* __restrict__ Wl,
                                               float* __restrict__ D,
                                               int R, int RW) {
  const int mt = blockIdx.x, b = blockIdx.y;
  const int tid = threadIdx.x, lane = tid & 63, wid = tid >> 6;
  __shared__ unsigned int As[64 * 32];    //  8 KB
  __shared__ unsigned int Bs[NB * 32];    // 40 KB
  f32x16 acc[5];
#pragma unroll
  for (int f = 0; f < 5; ++f)
#pragma unroll
    for (int i = 0; i < 16; ++i) acc[f][i] = 0.f;

  const unsigned int* Sb = Sp + (size_t)b * ((size_t)R * SC1);
  // ---- staging maps ----
  // A: 512 items; each thread 2 items; item -> (row, sub of 4 uints)
  const int aq0 = tid, aq1 = tid + 256;
  const int ar0 = aq0 >> 3, as0 = aq0 & 7;
  const int ar1 = aq1 >> 3, as1 = aq1 & 7;
  int art0 = mt * 64 + ar0; if (art0 > RW - 1) art0 = RW - 1;
  int art1 = mt * 64 + ar1; if (art1 > RW - 1) art1 = RW - 1;
  const unsigned int* aP0 = Sb + (size_t)art0 * SC1 + as0 * 4;
  const unsigned int* aP1 = Sb + (size_t)art1 * SC1 + as1 * 4;
  const int aw0 = ar0 * 32 + ((as0 >> 1) ^ (ar0 & 3)) * 4 + (as0 & 1) * 2;
  const int aw1 = ar1 * 32 + ((as1 >> 1) ^ (ar1 & 3)) * 4 + (as1 & 1) * 2;
  // B: 2560 uint4 items: item -> (n, half, unit); bP in USHORT units
  int bw[10];
  const ushort_t* bP[10];
#pragma unroll
  for (int p = 0; p < 10; ++p) {
    int q = tid + p * 256;
    int n = q >> 3, sub = q & 7, half = sub >> 2, unit = sub & 3;
    bP[p] = (half ? Wl : Wh) + (size_t)n * KB2 + unit * 8;
    bw[p] = n * 32 + half * 16 + ((unit ^ (n & 3)) * 4);
  }

  unsigned int ra0x, ra0y, ra0z, ra0w, ra1x, ra1y, ra1z, ra1w;
  uint4 rb0, rb1, rb2, rb3, rb4, rb5, rb6, rb7, rb8, rb9;

#define GLOADA(c0) { \
    uint2 t0 = *(const uint2*)(aP0 + (c0));      \
    uint2 t1 = *(const uint2*)(aP0 + (c0) + 2);  \
    uint2 t2 = *(const uint2*)(aP1 + (c0));      \
    uint2 t3 = *(const uint2*)(aP1 + (c0) + 2);  \
    ra0x = t0.x; ra0y = t0.y; ra0z = t1.x; ra0w = t1.y; \
    ra1x = t2.x; ra1y = t2.y; ra1z = t3.x; ra1w = t3.y; }
// c0 is a CHANNEL offset; bP is ushort* with 1 ushort per channel (r7 bug: *2)
#define GLOADB(c0) { \
    rb0 = *(const uint4*)(bP[0] + (c0)); rb1 = *(const uint4*)(bP[1] + (c0)); \
    rb2 = *(const uint4*)(bP[2] + (c0)); rb3 = *(const uint4*)(bP[3] + (c0)); \
    rb4 = *(const uint4*)(bP[4] + (c0)); rb5 = *(const uint4*)(bP[5] + (c0)); \
    rb6 = *(const uint4*)(bP[6] + (c0)); rb7 = *(const uint4*)(bP[7] + (c0)); \
    rb8 = *(const uint4*)(bP[8] + (c0)); rb9 = *(const uint4*)(bP[9] + (c0)); }
#define SSTORE() { \
    uint2 h0, l0, h1, l1; \
    h0.x = __builtin_amdgcn_perm(ra0y, ra0x, 0x07060302u); \
    h0.y = __builtin_amdgcn_perm(ra0w, ra0z, 0x07060302u); \
    l0.x = __builtin_amdgcn_perm(ra0y, ra0x, 0x05040100u); \
    l0.y = __builtin_amdgcn_perm(ra0w, ra0z, 0x05040100u); \
    h1.x = __builtin_amdgcn_perm(ra1y, ra1x, 0x07060302u); \
    h1.y = __builtin_amdgcn_perm(ra1w, ra1z, 0x07060302u); \
    l1.x = __builtin_amdgcn_perm(ra1y, ra1x, 0x05040100u); \
    l1.y = __builtin_amdgcn_perm(ra1w, ra1z, 0x05040100u); \
    *(uint2*)&As[aw0] = h0; *(uint2*)&As[aw0 + 16] = l0; \
    *(uint2*)&As[aw1] = h1; *(uint2*)&As[aw1 + 16] = l1; \
    *(uint4*)&Bs[bw[0]] = rb0; *(uint4*)&Bs[bw[1]] = rb1; \
    *(uint4*)&Bs[bw[2]] = rb2; *(uint4*)&Bs[bw[3]] = rb3; \
    *(uint4*)&Bs[bw[4]] = rb4; *(uint4*)&Bs[bw[5]] = rb5; \
    *(uint4*)&Bs[bw[6]] = rb6; *(uint4*)&Bs[bw[7]] = rb7; \
    *(uint4*)&Bs[bw[8]] = rb8; *(uint4*)&Bs[bw[9]] = rb9; }

  GLOADA(0); GLOADB(0);
  SSTORE();
  __syncthreads();

  const int wm = wid >> 1, wn = wid & 1;
  const int rA = wm * 32 + (lane & 31);
  const int rAsw = rA & 3;
  const int nbase = wn * 160 + (lane & 31);

  for (int ch = 0; ch < NCH2; ++ch) {
    if (ch + 1 < NCH2) { GLOADA((ch + 1) * 32); GLOADB((ch + 1) * 32); }
#pragma unroll
    for (int ks = 0; ks < 2; ++ks) {
      const int kga = ks * 2 + (lane >> 5);
      const short8 ah = *(const short8*)&As[rA * 32 + ((kga ^ rAsw) * 4)];
      const short8 al = *(const short8*)&As[rA * 32 + ((kga ^ rAsw) * 4) + 16];
#pragma unroll
      for (int nf = 0; nf < 5; ++nf) {
        const int nB = nbase + nf * 32;
        const int bo = nB * 32 + ((kga ^ (nB & 3)) * 4);
        const short8 bh = *(const short8*)&Bs[bo];
        const short8 bl = *(const short8*)&Bs[bo + 16];
        acc[nf] = __builtin_amdgcn_mfma_f32_32x32x16_bf16(ah, bh, acc[nf], 0, 0, 0);
        acc[nf] = __builtin_amdgcn_mfma_f32_32x32x16_bf16(ah, bl, acc[nf], 0, 0, 0);
        acc[nf] = __builtin_amdgcn_mfma_f32_32x32x16_bf16(al, bh, acc[nf], 0, 0, 0);
      }
    }
    __syncthreads();
    if (ch + 1 < NCH2) { SSTORE(); __syncthreads(); }
  }
#undef GLOADA
#undef GLOADB
#undef SSTORE

  // D write: row = mt*64 + wm*32 + crow(q,lane); col = wn*160 + nf*32 + lane&31
#pragma unroll
  for (int nf = 0; nf < 5; ++nf) {
#pragma unroll
    for (int q = 0; q < 16; ++q) {
      int crow = (q & 3) + 8 * (q >> 2) + 4 * (lane >> 5);
      int rl = mt * 64 + wm * 32 + crow;
      if (rl < RW)
        D[((size_t)b * R + rl) * NB + wn * 160 + nf * 32 + (lane & 31)] = acc[nf][q];
    }
  }
}

// ---------------- P2 window: tap-shift + bias + relu @ w2 + time ------------
__global__ __launch_bounds__(256) void k_p2w(const float* __restrict__ D,
                                             const float* __restrict__ bias,
                                             const float* __restrict__ w2,
                                             const float* __restrict__ b2,
                                             float* __restrict__ P2,
                                             int w0, int WTcur, int R) {
  int warp = blockIdx.x * 4 + (threadIdx.x >> 6);
  int lane = threadIdx.x & 63;
  if (warp >= BATCH * WTcur) return;
  int b = warp / WTcur, tl = warp % WTcur;
  int t = w0 + tl;
  float v = bias[lane];
#pragma unroll
  for (int tap = 0; tap < 5; ++tap)
    v += D[((size_t)b * R + tl + tap) * NB + tap * 64 + lane];
  v = fmaxf(v, 0.f);
  float* o = P2 + ((size_t)b * TOUT + t) * 9;
#pragma unroll
  for (int oo = 0; oo < 8; ++oo) {
    float s = v * w2[oo * 64 + lane];
    for (int d = 32; d; d >>= 1) s += __shfl_xor(s, d);
    if (lane == oo) o[1 + oo] = s + b2[oo];
  }
  if (lane == 8) o[0] = (float)t * (1.0f / 246.0f);
}

// ---------------- final signature pass A: chunk totals ----------------------
__global__ __launch_bounds__(256) void k_sig2A(const float* __restrict__ P2,
                                               float* __restrict__ T2) {
  int ch = blockIdx.x, b = blockIdx.y, tid = threadIdx.x;
  int r0 = ch * 16;
  int steps = 246 - r0; if (steps > 16) steps = 16;
  const float* p = P2 + (size_t)b * TOUT * 9;
  __shared__ float a1s[9], a2s[81], vs[2][9], b2s[2][81];
  float a3[3];
  int ia[3], i2[3], il2[3], ik[3];
#pragma unroll
  for (int n = 0; n < 3; ++n) {
    int e = tid + n * 256;
    ia[n] = e / 81; i2[n] = e / 9; il2[n] = e % 81; ik[n] = e % 9;
  }
  {
    int r = r0;
    if (tid < 9) vs[0][tid] = p[(r + 1) * 9 + tid] - p[r * 9 + tid];
    if (tid < 81) {
      int j = tid / 9, k = tid % 9;
      b2s[0][tid] = 0.5f * (p[(r + 1) * 9 + j] - p[r * 9 + j])
                         * (p[(r + 1) * 9 + k] - p[r * 9 + k]);
    }
  }
  __syncthreads();
  for (int s = 0; s < steps; ++s) {
    int buf = s & 1, r = r0 + s;
    float c1n = 0.f, c2n = 0.f;
    if (s == 0) {
      if (tid < 9)  c1n = vs[buf][tid];
      if (tid < 81) c2n = b2s[buf][tid];
#pragma unroll
      for (int n = 0; n < 3; ++n) {
        int e = tid + n * 256;
        if (e < 729) a3[n] = vs[buf][ia[n]] * b2s[buf][il2[n]] * (1.f / 3.f);
      }
    } else {
#pragma unroll
      for (int n = 0; n < 3; ++n) {
        int e = tid + n * 256;
        if (e < 729)
          a3[n] += (a1s[ia[n]] + vs[buf][ia[n]] * (1.f / 3.f)) * b2s[buf][il2[n]]
                 + a2s[i2[n]] * vs[buf][ik[n]];
      }
      if (tid < 81) c2n = a2s[tid] + b2s[buf][tid] + a1s[tid / 9] * vs[buf][tid % 9];
      if (tid < 9)  c1n = a1s[tid] + vs[buf][tid];
    }
    __syncthreads();
    if (tid < 9)  a1s[tid] = c1n;
    if (tid < 81) a2s[tid] = c2n;
    if (s + 1 < steps) {
      int r2 = r + 1, nb = buf ^ 1;
      if (tid < 9) vs[nb][tid] = p[(r2 + 1) * 9 + tid] - p[r2 * 9 + tid];
      if (tid < 81) {
        int j = tid / 9, k = tid % 9;
        b2s[nb][tid] = 0.5f * (p[(r2 + 1) * 9 + j] - p[r2 * 9 + j])
                            * (p[(r2 + 1) * 9 + k] - p[r2 * 9 + k]);
      }
    }
    __syncthreads();
  }
  {
    float* tb = T2 + ((size_t)b * 16 + ch) * SC2;
    if (tid < 9)  tb[tid] = a1s[tid];
    if (tid < 81) tb[9 + tid] = a2s[tid];
#pragma unroll
    for (int n = 0; n < 3; ++n) {
      int e = tid + n * 256;
      if (e < 729) tb[90 + e] = a3[n];
    }
  }
}

// ---------------- final signature pass B: fold 16 totals --------------------
__global__ __launch_bounds__(256) void k_sig2B(const float* __restrict__ T2,
                                               float* __restrict__ sg) {
  int b = blockIdx.x, tid = threadIdx.x;
  __shared__ float a1s[9], a2s[81], b1s[9], b2s[81];
  float a3[3], b3[3];
  int ia[3], i2[3], il2[3], ik[3];
#pragma unroll
  for (int n = 0; n < 3; ++n) {
    int e = tid + n * 256;
    ia[n] = e / 81; i2[n] = e / 9; il2[n] = e % 81; ik[n] = e % 9;
  }
  const float* base = T2 + (size_t)b * 16 * SC2;
  if (tid < 9)  a1s[tid] = base[tid];
  if (tid < 81) a2s[tid] = base[9 + tid];
#pragma unroll
  for (int n = 0; n < 3; ++n) { int e = tid + n * 256; if (e < 729) a3[n] = base[90 + e]; }
  __syncthreads();
  for (int ch = 1; ch < 16; ++ch) {
    const float* sl = base + (size_t)ch * SC2;
    if (tid < 9)  b1s[tid] = sl[tid];
    if (tid < 81) b2s[tid] = sl[9 + tid];
#pragma unroll
    for (int n = 0; n < 3; ++n) { int e = tid + n * 256; if (e < 729) b3[n] = sl[90 + e]; }
    __syncthreads();
#pragma unroll
    for (int n = 0; n < 3; ++n) {
      int e = tid + n * 256;
      if (e < 729) a3[n] += b3[n] + a1s[ia[n]] * b2s[il2[n]] + a2s[i2[n]] * b1s[ik[n]];
    }
    float c1n = 0.f, c2n = 0.f;
    if (tid < 81) c2n = a2s[tid] + b2s[tid] + a1s[tid / 9] * b1s[tid % 9];
    if (tid < 9)  c1n = a1s[tid] + b1s[tid];
    __syncthreads();
    if (tid < 9)  a1s[tid] = c1n;
    if (tid < 81) a2s[tid] = c2n;
    __syncthreads();
  }
  float* o = sg + (size_t)b * SC2;
  if (tid < 9)  o[tid] = a1s[tid];
  if (tid < 81) o[9 + tid] = a2s[tid];
#pragma unroll
  for (int n = 0; n < 3; ++n) { int e = tid + n * 256; if (e < 729) o[90 + e] = a3[n]; }
}

// ---------------- linear + softmax -----------------------------------------
__global__ __launch_bounds__(64) void k_final(const float* __restrict__ sg,
                                              const float* __restrict__ lw,
                                              const float* __restrict__ lb,
                                              float* __restrict__ out) {
  int b = blockIdx.x, lane = threadIdx.x;
  float logit = -3.402823466e38f;
  if (lane < NSTK) {
    float s = lb[lane];
    const float* w = lw + (size_t)lane * SC2;
    const float* g = sg + (size_t)b * SC2;
    for (int c = 0; c < SC2; ++c) s += g[c] * w[c];
    logit = s;
  }
  float m = logit;
  for (int d = 32; d; d >>= 1) m = fmaxf(m, __shfl_xor(m, d));
  float e = (lane < NSTK) ? expf(logit - m) : 0.f;
  float sum = e;
  for (int d = 32; d; d >>= 1) sum += __shfl_xor(sum, d);
  if (lane < NSTK) out[(size_t)b * NSTK + lane] = e / sum;
}

// ---------------------------------------------------------------------------
extern "C" void kernel_launch(void* const* d_in, const int* in_sizes, int n_in,
                              void* d_out, int out_size, void* d_ws, size_t ws_size,
                              hipStream_t stream) {
  const float* x      = (const float*)d_in[0];
  const float* gamma  = (const float*)d_in[1];
  const float* beta   = (const float*)d_in[2];
  const float* a1w1   = (const float*)d_in[3];
  const float* a1b1   = (const float*)d_in[4];
  const float* a1w2   = (const float*)d_in[5];
  const float* a1b2   = (const float*)d_in[6];
  const float* a2w1   = (const float*)d_in[7];
  const float* a2b1   = (const float*)d_in[8];
  const float* a2w2   = (const float*)d_in[9];
  const float* a2b2   = (const float*)d_in[10];
  const float* lin_w  = (const float*)d_in[11];
  const float* lin_b  = (const float*)d_in[12];
  float* out = (float*)d_out;

  float* ws = (float*)d_ws;
  // fixed prefix (floats):
  float*    scale = ws;                   //       256
  float*    shift = ws + 256;             //       256
  float*    P1    = ws + 512;             //   451,584
  ushort_t* Wh2   = (ushort_t*)(ws + 452096);   // 320*2976 ushorts = 476,160 fl
  ushort_t* Wl2   = (ushort_t*)(ws + 928256);   // 476,160 fl
  float*    carry = ws + 1404416;         //   378,112
  float*    Pfx   = ws + 1782528;         // 16 x 378,112 = 6,049,792
  float*    P2    = ws + 7832320;         //   284,544
  float*    sig2  = ws + 8116864;         //   104,832
  const size_t off_D = 8221696;
  float*    T2    = Pfx;                  // Pfx dead after last scanC

  size_t ws_floats = ws_size / 4;
  long slot = (long)BATCH * SC1;                 // 378,112 per stream row
  long perR = (long)BATCH * NB + slot;           // D row + stream row = 419,072
  long avail = (long)ws_floats - (long)off_D - 1024;
  int R = (int)(avail > 0 ? avail / perR : 0);
  if (R > 116) R = 116;                          // cap: window stays L3-resident
  if (R < 24)  R = 24;                           // floor proven safe (r3/r5/r6)
  float* D    = ws + off_D;
  float* Swin = ws + off_D + (size_t)BATCH * R * NB;

  int WT = ((R - 4) / 16) * 16;
  int nwin = (TOUT + WT - 1) / WT;

  hipMemsetAsync(carry, 0, (size_t)slot * 4, stream);   // chen identity = zeros

  k_bn  <<<LSEQ, 256, 0, stream>>>(x, gamma, beta, scale, shift);
  k_aug1<<<(BATCH * L1P) / 256, 256, 0, stream>>>(x, scale, shift, a1w1, a1b1, a1w2, a1b2, P1);
  k_wt3 <<<(NB * KB2 + 255) / 256, 256, 0, stream>>>(a2w1, Wh2, Wl2);

  for (int w = 0; w < nwin; ++w) {
    int w0 = w * WT;
    int WTcur = TOUT - w0; if (WTcur > WT) WTcur = WT;
    int RW = WTcur + 4;
    int NC = (RW + 15) / 16;
    int NCC = (w + 1 < nwin) ? (WT / 16) : -2;
    k_scanA<<<dim3(NC, BATCH), 256, 0, stream>>>(P1, Swin, R, w0, RW);
    k_scanB<<<BATCH, 256, 0, stream>>>(Swin, Pfx, carry, R, RW, NC, NCC);
    k_scanC3<<<dim3(NC, BATCH), 256, 0, stream>>>(Swin, Pfx, R, RW);
    int mt = (RW + 63) / 64;
    k_gemm5<<<dim3(mt, BATCH), 256, 0, stream>>>(
        (const unsigned int*)Swin, Wh2, Wl2, D, R, RW);
    int np2 = BATCH * WTcur;
    k_p2w<<<(np2 + 3) / 4, 256, 0, stream>>>(D, a2b1, a2w2, a2b2, P2, w0, WTcur, R);
  }

  k_sig2A<<<dim3(16, BATCH), 256, 0, stream>>>(P2, T2);
  k_sig2B<<<BATCH, 256, 0, stream>>>(T2, sig2);
  k_final<<<BATCH, 64, 0, stream>>>(sig2, lin_w, lin_b, out);
}